// Round 1
// baseline (709.573 us; speedup 1.0000x reference)
//
#include <hip/hip_runtime.h>

#define EPS 1e-5f

// ---- d_ws layout (float offsets) ----
#define W1OT 0          //   486  offset1_w transposed [c*9+t][18]
#define W1T  512        //  1728  conv1_w   transposed [c*9+t][64]
#define W2OT 2304       // 10368  offset2_w transposed [c*9+t][18]
#define W2T  12800      // 73728  conv2_w   transposed [c*9+t][128]
#define SC1  86528      //    64  bn1 scale
#define SH1  86592      //    64  bn1 shift (bias folded)
#define SC2  86656      //   128  bn2 scale
#define SH2  86784      //   128  bn2 shift (bias folded)
#define POOL 86912      //  4096  pooled sums (zeroed in prep)
#define FC1O 91008      //  8192  fc1 activations
#define OFF1 99328      // 2359296  (32,18,64,64)
#define H1   2458624    // 8388608  (32,64,64,64)
#define OFF2 10847232   // 2359296  (32,18,64,64)
// total 13206528 floats = 50.4 MiB

struct Tap { int i00, i01, i10, i11; float w00, w01, w10, w11; };

__device__ __forceinline__ Tap make_tap(float py, float px) {
    float y0f = floorf(py), x0f = floorf(px);
    float wy = py - y0f, wx = px - x0f;
    bool by0 = (y0f >= 0.f)  && (y0f < 64.f);
    bool by1 = (y0f >= -1.f) && (y0f < 63.f);   // y0+1 in [0,64)
    bool bx0 = (x0f >= 0.f)  && (x0f < 64.f);
    bool bx1 = (x0f >= -1.f) && (x0f < 63.f);
    int y0 = min(max((int)y0f, 0), 63);
    int y1 = min(max((int)y0f + 1, 0), 63);
    int x0 = min(max((int)x0f, 0), 63);
    int x1 = min(max((int)x0f + 1, 0), 63);
    Tap tp;
    tp.i00 = y0 * 64 + x0; tp.i01 = y0 * 64 + x1;
    tp.i10 = y1 * 64 + x0; tp.i11 = y1 * 64 + x1;
    tp.w00 = (by0 && bx0) ? (1.f - wy) * (1.f - wx) : 0.f;
    tp.w01 = (by0 && bx1) ? (1.f - wy) * wx         : 0.f;
    tp.w10 = (by1 && bx0) ? wy * (1.f - wx)         : 0.f;
    tp.w11 = (by1 && bx1) ? wy * wx                 : 0.f;
    return tp;
}

// ---- prep: weight transposes + BN folding + pool zero ----
__global__ __launch_bounds__(256) void k_prep(
    const float* __restrict__ o1w, const float* __restrict__ c1w,
    const float* __restrict__ o2w, const float* __restrict__ c2w,
    const float* __restrict__ c1b, const float* __restrict__ g1,
    const float* __restrict__ be1, const float* __restrict__ m1,
    const float* __restrict__ v1,
    const float* __restrict__ c2b, const float* __restrict__ g2,
    const float* __restrict__ be2, const float* __restrict__ m2,
    const float* __restrict__ v2,
    float* __restrict__ ws) {
    int tid = blockIdx.x * 256 + threadIdx.x;
    if (tid < 486) {
        int k = tid / 18, co = tid - k * 18, c = k / 9, t = k - c * 9;
        ws[W1OT + tid] = o1w[(co * 3 + c) * 9 + t];
    } else if (tid < 2214) {
        int i = tid - 486;
        int k = i >> 6, co = i & 63, c = k / 9, t = k - c * 9;
        ws[W1T + i] = c1w[(co * 3 + c) * 9 + t];
    } else if (tid < 12582) {
        int i = tid - 2214;
        int k = i / 18, co = i - k * 18, c = k / 9, t = k - c * 9;
        ws[W2OT + i] = o2w[(co * 64 + c) * 9 + t];
    } else if (tid < 86310) {
        int i = tid - 12582;
        int k = i >> 7, co = i & 127, c = k / 9, t = k - c * 9;
        ws[W2T + i] = c2w[(co * 64 + c) * 9 + t];
    } else if (tid < 86374) {
        int i = tid - 86310;
        float s = g1[i] * rsqrtf(v1[i] + EPS);
        ws[SC1 + i] = s;
        ws[SH1 + i] = (c1b[i] - m1[i]) * s + be1[i];
    } else if (tid < 86502) {
        int i = tid - 86374;
        float s = g2[i] * rsqrtf(v2[i] + EPS);
        ws[SC2 + i] = s;
        ws[SH2 + i] = (c2b[i] - m2[i]) * s + be2[i];
    } else if (tid < 90598) {
        ws[POOL + tid - 86502] = 0.f;
    }
}

// ---- offset conv1: x(32,3,64,64) -> off1(32,18,64,64), 3x3 SAME ----
__global__ __launch_bounds__(256, 2) void k_off1(
    const float* __restrict__ x, const float* __restrict__ o1b,
    float* __restrict__ ws) {
    int tid = blockIdx.x * 256 + threadIdx.x;
    int b = tid >> 12, hw = tid & 4095, h = hw >> 6, w = hw & 63;
    const float* wt = ws + W1OT;
    float acc[18];
#pragma unroll
    for (int i = 0; i < 18; ++i) acc[i] = 0.f;
    for (int c = 0; c < 3; ++c) {
        const float* ip = x + (b * 3 + c) * 4096;
#pragma unroll
        for (int t = 0; t < 9; ++t) {
            int yy = h + t / 3 - 1, xx = w + t % 3 - 1;
            float pv = (yy >= 0 && yy < 64 && xx >= 0 && xx < 64) ? ip[yy * 64 + xx] : 0.f;
            const float* wp = wt + (c * 9 + t) * 18;
#pragma unroll
            for (int co = 0; co < 18; ++co) acc[co] += pv * wp[co];
        }
    }
    float* op = ws + OFF1 + b * 18 * 4096 + hw;
#pragma unroll
    for (int co = 0; co < 18; ++co) op[co * 4096] = acc[co] + o1b[co];
}

// ---- deform conv1 (3->64) + BN + ReLU -> h1(32,64,64,64) ----
__global__ __launch_bounds__(256, 2) void k_def1(
    const float* __restrict__ x, float* __restrict__ ws) {
    int tid = blockIdx.x * 256 + threadIdx.x;
    int b = tid >> 12, hw = tid & 4095, h = hw >> 6, w = hw & 63;
    const float* offp = ws + OFF1 + b * 18 * 4096 + hw;
    float v[27];
#pragma unroll
    for (int t = 0; t < 9; ++t) {
        float dy = offp[(2 * t) * 4096];
        float dx = offp[(2 * t + 1) * 4096];
        Tap tp = make_tap((float)(h + t / 3 - 1) + dy, (float)(w + t % 3 - 1) + dx);
#pragma unroll
        for (int c = 0; c < 3; ++c) {
            const float* ip = x + (b * 3 + c) * 4096;
            v[c * 9 + t] = tp.w00 * ip[tp.i00] + tp.w01 * ip[tp.i01]
                         + tp.w10 * ip[tp.i10] + tp.w11 * ip[tp.i11];
        }
    }
    float acc[64];
#pragma unroll
    for (int i = 0; i < 64; ++i) acc[i] = 0.f;
    const float* wt = ws + W1T;
#pragma unroll
    for (int k = 0; k < 27; ++k) {
        float vk = v[k];
        const float* wp = wt + k * 64;
#pragma unroll
        for (int co = 0; co < 64; ++co) acc[co] += vk * wp[co];
    }
    const float* sc = ws + SC1;
    const float* sh = ws + SH1;
    float* op = ws + H1 + b * 64 * 4096 + hw;
#pragma unroll
    for (int co = 0; co < 64; ++co)
        op[co * 4096] = fmaxf(acc[co] * sc[co] + sh[co], 0.f);
}

// ---- offset conv2: h1(32,64,..) -> off2(32,18,..), 3x3 SAME ----
__global__ __launch_bounds__(256, 2) void k_off2(
    const float* __restrict__ o2b, float* __restrict__ ws) {
    int tid = blockIdx.x * 256 + threadIdx.x;
    int b = tid >> 12, hw = tid & 4095, h = hw >> 6, w = hw & 63;
    float acc[18];
#pragma unroll
    for (int i = 0; i < 18; ++i) acc[i] = 0.f;
    const float* h1p = ws + H1 + b * 64 * 4096;
    const float* wt = ws + W2OT;
    for (int c = 0; c < 64; ++c) {
        const float* ip = h1p + c * 4096;
#pragma unroll
        for (int t = 0; t < 9; ++t) {
            int yy = h + t / 3 - 1, xx = w + t % 3 - 1;
            float pv = (yy >= 0 && yy < 64 && xx >= 0 && xx < 64) ? ip[yy * 64 + xx] : 0.f;
            const float* wp = wt + (c * 9 + t) * 18;
#pragma unroll
            for (int co = 0; co < 18; ++co) acc[co] += pv * wp[co];
        }
    }
    float* op = ws + OFF2 + b * 18 * 4096 + hw;
#pragma unroll
    for (int co = 0; co < 18; ++co) op[co * 4096] = acc[co] + o2b[co];
}

// ---- deform conv2 (64->128) + BN + ReLU + global-avg-pool (atomic sums) ----
__global__ __launch_bounds__(256, 2) void k_def2(float* __restrict__ ws) {
    int tid = blockIdx.x * 256 + threadIdx.x;
    int b = tid >> 12, hw = tid & 4095, h = hw >> 6, w = hw & 63;
    int lane = threadIdx.x & 63;
    float acc[128];
#pragma unroll
    for (int i = 0; i < 128; ++i) acc[i] = 0.f;
    const float* offp = ws + OFF2 + b * 18 * 4096 + hw;
    const float* h1p = ws + H1 + b * 64 * 4096;
    const float* wt = ws + W2T;
#pragma unroll
    for (int t = 0; t < 9; ++t) {
        float dy = offp[(2 * t) * 4096];
        float dx = offp[(2 * t + 1) * 4096];
        Tap tp = make_tap((float)(h + t / 3 - 1) + dy, (float)(w + t % 3 - 1) + dx);
        for (int c = 0; c < 64; ++c) {
            const float* ip = h1p + c * 4096;
            float v = tp.w00 * ip[tp.i00] + tp.w01 * ip[tp.i01]
                    + tp.w10 * ip[tp.i10] + tp.w11 * ip[tp.i11];
            const float* wp = wt + (c * 9 + t) * 128;
#pragma unroll
            for (int co = 0; co < 128; ++co) acc[co] += v * wp[co];
        }
    }
    const float* sc = ws + SC2;
    const float* sh = ws + SH2;
    float* pool = ws + POOL;
#pragma unroll
    for (int co = 0; co < 128; ++co) {
        float r = fmaxf(acc[co] * sc[co] + sh[co], 0.f);
        r += __shfl_xor(r, 1);
        r += __shfl_xor(r, 2);
        r += __shfl_xor(r, 4);
        r += __shfl_xor(r, 8);
        r += __shfl_xor(r, 16);
        r += __shfl_xor(r, 32);
        if (lane == 0) atomicAdd(&pool[b * 128 + co], r);
    }
}

// ---- fc1 + relu ----
__global__ __launch_bounds__(256) void k_fc1(
    const float* __restrict__ w, const float* __restrict__ bias,
    float* __restrict__ ws) {
    int b = blockIdx.x, o = threadIdx.x;
    __shared__ float pl[128];
    if (o < 128) pl[o] = ws[POOL + b * 128 + o] * (1.f / 4096.f);
    __syncthreads();
    float s = bias[o];
    const float* wp = w + o * 128;
#pragma unroll 8
    for (int c = 0; c < 128; ++c) s += pl[c] * wp[c];
    ws[FC1O + b * 256 + o] = fmaxf(s, 0.f);
}

// ---- fc2 ----
__global__ __launch_bounds__(256) void k_fc2(
    const float* __restrict__ w, const float* __restrict__ bias,
    const float* __restrict__ ws, float* __restrict__ out) {
    int b = blockIdx.x, o = threadIdx.x;
    __shared__ float hl[256];
    hl[o] = ws[FC1O + b * 256 + o];
    __syncthreads();
    if (o < 200) {
        float s = bias[o];
        const float* wp = w + o * 256;
#pragma unroll 8
        for (int c = 0; c < 256; ++c) s += hl[c] * wp[c];
        out[b * 200 + o] = s;
    }
}

extern "C" void kernel_launch(void* const* d_in, const int* in_sizes, int n_in,
                              void* d_out, int out_size, void* d_ws, size_t ws_size,
                              hipStream_t stream) {
    const float* x   = (const float*)d_in[0];
    const float* o1w = (const float*)d_in[1];
    const float* o1b = (const float*)d_in[2];
    const float* c1w = (const float*)d_in[3];
    const float* c1b = (const float*)d_in[4];
    const float* g1  = (const float*)d_in[5];
    const float* be1 = (const float*)d_in[6];
    const float* m1  = (const float*)d_in[7];
    const float* v1  = (const float*)d_in[8];
    const float* o2w = (const float*)d_in[9];
    const float* o2b = (const float*)d_in[10];
    const float* c2w = (const float*)d_in[11];
    const float* c2b = (const float*)d_in[12];
    const float* g2  = (const float*)d_in[13];
    const float* be2 = (const float*)d_in[14];
    const float* m2  = (const float*)d_in[15];
    const float* v2  = (const float*)d_in[16];
    const float* f1w = (const float*)d_in[17];
    const float* f1b = (const float*)d_in[18];
    const float* f2w = (const float*)d_in[19];
    const float* f2b = (const float*)d_in[20];
    float* ws  = (float*)d_ws;
    float* out = (float*)d_out;

    k_prep<<<354, 256, 0, stream>>>(o1w, c1w, o2w, c2w,
                                    c1b, g1, be1, m1, v1,
                                    c2b, g2, be2, m2, v2, ws);
    k_off1<<<512, 256, 0, stream>>>(x, o1b, ws);
    k_def1<<<512, 256, 0, stream>>>(x, ws);
    k_off2<<<512, 256, 0, stream>>>(o2b, ws);
    k_def2<<<512, 256, 0, stream>>>(ws);
    k_fc1<<<32, 256, 0, stream>>>(f1w, f1b, ws);
    k_fc2<<<32, 256, 0, stream>>>(f2w, f2b, ws, out);
}

// Round 2
// 518.446 us; speedup vs baseline: 1.3687x; 1.3687x over previous
//
#include <hip/hip_runtime.h>

#define EPS 1e-5f

// ---- d_ws layout (float offsets) ----
#define W1OT 0          //   486  offset1_w transposed [c*9+t][18]
#define W1T  512        //  1728  conv1_w   transposed [c*9+t][64]
#define W2OT 2304       // 10368  offset2_w transposed [c*9+t][18]
#define W2T  12800      // 73728 ushorts: conv2_w bf16 [t][n=cout][c]  (36864 float-slots)
#define SC1  86528      //    64  bn1 scale
#define SH1  86592      //    64  bn1 shift (bias folded)
#define SC2  86656      //   128  bn2 scale
#define SH2  86784      //   128  bn2 shift (bias folded)
#define POOL 86912      //  4096  pooled sums (zeroed in prep)
#define FC1O 91008      //  8192  fc1 activations
#define OFF1 99328      // 2359296  (32,18,64,64)
#define H1   2458624    // 8388608  (32,64,64,64)
#define OFF2 10847232   // 2359296  (32,18,64,64)
// total 13206528 floats = 50.4 MiB

typedef __attribute__((ext_vector_type(8))) short bhalf8;
typedef __attribute__((ext_vector_type(4))) float f32x4;

#define BPAD 72   // LDS k-stride in bf16 elems: 144 B = 36 words -> 16B-aligned, <=2-way on frag reads

struct Tap { int i00, i01, i10, i11; float w00, w01, w10, w11; };

__device__ __forceinline__ Tap make_tap(float py, float px) {
    float y0f = floorf(py), x0f = floorf(px);
    float wy = py - y0f, wx = px - x0f;
    bool by0 = (y0f >= 0.f)  && (y0f < 64.f);
    bool by1 = (y0f >= -1.f) && (y0f < 63.f);   // y0+1 in [0,64)
    bool bx0 = (x0f >= 0.f)  && (x0f < 64.f);
    bool bx1 = (x0f >= -1.f) && (x0f < 63.f);
    int y0 = min(max((int)y0f, 0), 63);
    int y1 = min(max((int)y0f + 1, 0), 63);
    int x0 = min(max((int)x0f, 0), 63);
    int x1 = min(max((int)x0f + 1, 0), 63);
    Tap tp;
    tp.i00 = y0 * 64 + x0; tp.i01 = y0 * 64 + x1;
    tp.i10 = y1 * 64 + x0; tp.i11 = y1 * 64 + x1;
    tp.w00 = (by0 && bx0) ? (1.f - wy) * (1.f - wx) : 0.f;
    tp.w01 = (by0 && bx1) ? (1.f - wy) * wx         : 0.f;
    tp.w10 = (by1 && bx0) ? wy * (1.f - wx)         : 0.f;
    tp.w11 = (by1 && bx1) ? wy * wx                 : 0.f;
    return tp;
}

__device__ __forceinline__ ushort f2bf(float f) {
    union { float f; uint u; } a; a.f = f;
    uint u = a.u;
    uint r = (u + 0x7fffu + ((u >> 16) & 1u)) >> 16;   // RNE
    return (ushort)r;
}

// ---- prep: weight transposes + BN folding + pool zero ----
__global__ __launch_bounds__(256) void k_prep(
    const float* __restrict__ o1w, const float* __restrict__ c1w,
    const float* __restrict__ o2w, const float* __restrict__ c2w,
    const float* __restrict__ c1b, const float* __restrict__ g1,
    const float* __restrict__ be1, const float* __restrict__ m1,
    const float* __restrict__ v1,
    const float* __restrict__ c2b, const float* __restrict__ g2,
    const float* __restrict__ be2, const float* __restrict__ m2,
    const float* __restrict__ v2,
    float* __restrict__ ws) {
    int tid = blockIdx.x * 256 + threadIdx.x;
    if (tid < 486) {
        int k = tid / 18, co = tid - k * 18, c = k / 9, t = k - c * 9;
        ws[W1OT + tid] = o1w[(co * 3 + c) * 9 + t];
    } else if (tid < 2214) {
        int i = tid - 486;
        int k = i >> 6, co = i & 63, c = k / 9, t = k - c * 9;
        ws[W1T + i] = c1w[(co * 3 + c) * 9 + t];
    } else if (tid < 12582) {
        int i = tid - 2214;
        int k = i / 18, co = i - k * 18, c = k / 9, t = k - c * 9;
        ws[W2OT + i] = o2w[(co * 64 + c) * 9 + t];
    } else if (tid < 86310) {
        int i = tid - 12582;                 // i = t*8192 + n*64 + c
        int c = i & 63, n = (i >> 6) & 127, t = i >> 13;
        ((ushort*)(ws + W2T))[i] = f2bf(c2w[(n * 64 + c) * 9 + t]);
    } else if (tid < 86374) {
        int i = tid - 86310;
        float s = g1[i] * rsqrtf(v1[i] + EPS);
        ws[SC1 + i] = s;
        ws[SH1 + i] = (c1b[i] - m1[i]) * s + be1[i];
    } else if (tid < 86502) {
        int i = tid - 86374;
        float s = g2[i] * rsqrtf(v2[i] + EPS);
        ws[SC2 + i] = s;
        ws[SH2 + i] = (c2b[i] - m2[i]) * s + be2[i];
    } else if (tid < 90598) {
        ws[POOL + tid - 86502] = 0.f;
    }
}

// ---- offset conv1: x(32,3,64,64) -> off1(32,18,64,64), 3x3 SAME ----
__global__ __launch_bounds__(256, 2) void k_off1(
    const float* __restrict__ x, const float* __restrict__ o1b,
    float* __restrict__ ws) {
    int tid = blockIdx.x * 256 + threadIdx.x;
    int b = tid >> 12, hw = tid & 4095, h = hw >> 6, w = hw & 63;
    const float* wt = ws + W1OT;
    float acc[18];
#pragma unroll
    for (int i = 0; i < 18; ++i) acc[i] = 0.f;
    for (int c = 0; c < 3; ++c) {
        const float* ip = x + (b * 3 + c) * 4096;
#pragma unroll
        for (int t = 0; t < 9; ++t) {
            int yy = h + t / 3 - 1, xx = w + t % 3 - 1;
            float pv = (yy >= 0 && yy < 64 && xx >= 0 && xx < 64) ? ip[yy * 64 + xx] : 0.f;
            const float* wp = wt + (c * 9 + t) * 18;
#pragma unroll
            for (int co = 0; co < 18; ++co) acc[co] += pv * wp[co];
        }
    }
    float* op = ws + OFF1 + b * 18 * 4096 + hw;
#pragma unroll
    for (int co = 0; co < 18; ++co) op[co * 4096] = acc[co] + o1b[co];
}

// ---- deform conv1 (3->64) + BN + ReLU -> h1(32,64,64,64) ----
__global__ __launch_bounds__(256, 2) void k_def1(
    const float* __restrict__ x, float* __restrict__ ws) {
    int tid = blockIdx.x * 256 + threadIdx.x;
    int b = tid >> 12, hw = tid & 4095, h = hw >> 6, w = hw & 63;
    const float* offp = ws + OFF1 + b * 18 * 4096 + hw;
    float v[27];
#pragma unroll
    for (int t = 0; t < 9; ++t) {
        float dy = offp[(2 * t) * 4096];
        float dx = offp[(2 * t + 1) * 4096];
        Tap tp = make_tap((float)(h + t / 3 - 1) + dy, (float)(w + t % 3 - 1) + dx);
#pragma unroll
        for (int c = 0; c < 3; ++c) {
            const float* ip = x + (b * 3 + c) * 4096;
            v[c * 9 + t] = tp.w00 * ip[tp.i00] + tp.w01 * ip[tp.i01]
                         + tp.w10 * ip[tp.i10] + tp.w11 * ip[tp.i11];
        }
    }
    float acc[64];
#pragma unroll
    for (int i = 0; i < 64; ++i) acc[i] = 0.f;
    const float* wt = ws + W1T;
#pragma unroll
    for (int k = 0; k < 27; ++k) {
        float vk = v[k];
        const float* wp = wt + k * 64;
#pragma unroll
        for (int co = 0; co < 64; ++co) acc[co] += vk * wp[co];
    }
    const float* sc = ws + SC1;
    const float* sh = ws + SH1;
    float* op = ws + H1 + b * 64 * 4096 + hw;
#pragma unroll
    for (int co = 0; co < 64; ++co)
        op[co * 4096] = fmaxf(acc[co] * sc[co] + sh[co], 0.f);
}

// ---- offset conv2: h1(32,64,..) -> off2(32,18,..), 3x3 SAME ----
__global__ __launch_bounds__(256, 2) void k_off2(
    const float* __restrict__ o2b, float* __restrict__ ws) {
    int tid = blockIdx.x * 256 + threadIdx.x;
    int b = tid >> 12, hw = tid & 4095, h = hw >> 6, w = hw & 63;
    float acc[18];
#pragma unroll
    for (int i = 0; i < 18; ++i) acc[i] = 0.f;
    const float* h1p = ws + H1 + b * 64 * 4096;
    const float* wt = ws + W2OT;
    for (int c = 0; c < 64; ++c) {
        const float* ip = h1p + c * 4096;
#pragma unroll
        for (int t = 0; t < 9; ++t) {
            int yy = h + t / 3 - 1, xx = w + t % 3 - 1;
            float pv = (yy >= 0 && yy < 64 && xx >= 0 && xx < 64) ? ip[yy * 64 + xx] : 0.f;
            const float* wp = wt + (c * 9 + t) * 18;
#pragma unroll
            for (int co = 0; co < 18; ++co) acc[co] += pv * wp[co];
        }
    }
    float* op = ws + OFF2 + b * 18 * 4096 + hw;
#pragma unroll
    for (int co = 0; co < 18; ++co) op[co * 4096] = acc[co] + o2b[co];
}

// ---- deform conv2 (64->128) as implicit-GEMM bf16 MFMA + BN + ReLU + pool ----
// Grid: 2048 WGs; WG g = (b = g>>6, h-row = g&63); 256 thr = 4 waves.
// A[M=64px][K=576=t*64+c] gathered on the fly -> LDS bf16; B[K][N=128] bf16 staged per tap.
__global__ __launch_bounds__(256, 3) void k_def2(float* __restrict__ ws) {
    __shared__ ushort Alds[64 * BPAD];    // [px][c-in-tap]
    __shared__ ushort Blds[128 * BPAD];   // [n][c-in-tap]
    int g = blockIdx.x;
    int b = g >> 6, h = g & 63;
    int tid = threadIdx.x;
    int lane = tid & 63;
    int wv = tid >> 6;                    // wave 0..3
    // gather roles
    int px = tid & 63;                    // pixel x-coordinate = local row m
    int c0 = (tid >> 6) * 16;             // 16-channel chunk
    const float* h1p  = ws + H1 + b * 64 * 4096;
    const float* offp = ws + OFF2 + b * 18 * 4096 + h * 64 + px;
    const ushort* wB  = (const ushort*)(ws + W2T);   // [t][n][c] bf16
    // B staging role
    int bn = tid >> 1, bc = (tid & 1) * 32;

    f32x4 acc[8];
#pragma unroll
    for (int i = 0; i < 8; ++i) acc[i] = (f32x4)0.f;

    for (int t = 0; t < 9; ++t) {
        if (t) __syncthreads();           // protect LDS from previous MFMA readers
        // ---- stage B slice: 128 x 64 bf16 ----
        {
            const uint4* s4 = (const uint4*)(wB + (t * 128 + bn) * 64 + bc);
            uint4 v0 = s4[0], v1 = s4[1], v2 = s4[2], v3 = s4[3];
            ushort* dst = Blds + bn * BPAD + bc;
            *(uint4*)(dst)      = v0;
            *(uint4*)(dst + 8)  = v1;
            *(uint4*)(dst + 16) = v2;
            *(uint4*)(dst + 24) = v3;
        }
        // ---- gather A slice: this thread = (px, channels c0..c0+15) ----
        {
            float dy = offp[(2 * t) * 4096];
            float dx = offp[(2 * t + 1) * 4096];
            Tap tp = make_tap((float)(h + t / 3 - 1) + dy,
                              (float)(px + t % 3 - 1) + dx);
            ushort vals[16];
#pragma unroll
            for (int cc = 0; cc < 16; ++cc) {
                const float* ip = h1p + (c0 + cc) * 4096;
                float v = tp.w00 * ip[tp.i00] + tp.w01 * ip[tp.i01]
                        + tp.w10 * ip[tp.i10] + tp.w11 * ip[tp.i11];
                vals[cc] = f2bf(v);
            }
            ushort* ad = Alds + px * BPAD + c0;
            *(uint4*)(ad)     = *(const uint4*)(vals);
            *(uint4*)(ad + 8) = *(const uint4*)(vals + 8);
        }
        __syncthreads();
        // ---- 2 MFMA K-steps of 32 ----
#pragma unroll
        for (int ks = 0; ks < 2; ++ks) {
            int ko = ks * 32 + ((lane >> 4) << 3);
            bhalf8 af = *(const bhalf8*)(Alds + (wv * 16 + (lane & 15)) * BPAD + ko);
#pragma unroll
            for (int nt = 0; nt < 8; ++nt) {
                bhalf8 bf = *(const bhalf8*)(Blds + (nt * 16 + (lane & 15)) * BPAD + ko);
                acc[nt] = __builtin_amdgcn_mfma_f32_16x16x32_bf16(af, bf, acc[nt], 0, 0, 0);
            }
        }
    }
    // ---- epilogue: BN + ReLU + pool (h2 never materialized) ----
    const float* sc = ws + SC2;
    const float* sh = ws + SH2;
    float* pool = ws + POOL;
#pragma unroll
    for (int nt = 0; nt < 8; ++nt) {
        int col = nt * 16 + (lane & 15);
        float s0 = sc[col], s1 = sh[col];
        float s = 0.f;
#pragma unroll
        for (int r = 0; r < 4; ++r)            // rows quad*4+r, col fixed
            s += fmaxf(acc[nt][r] * s0 + s1, 0.f);
        s += __shfl_xor(s, 16);                // sum the 4 quads (16 rows of this wave)
        s += __shfl_xor(s, 32);
        if (lane < 16) atomicAdd(&pool[b * 128 + col], s);
    }
}

// ---- fc1 + relu ----
__global__ __launch_bounds__(256) void k_fc1(
    const float* __restrict__ w, const float* __restrict__ bias,
    float* __restrict__ ws) {
    int b = blockIdx.x, o = threadIdx.x;
    __shared__ float pl[128];
    if (o < 128) pl[o] = ws[POOL + b * 128 + o] * (1.f / 4096.f);
    __syncthreads();
    float s = bias[o];
    const float* wp = w + o * 128;
#pragma unroll 8
    for (int c = 0; c < 128; ++c) s += pl[c] * wp[c];
    ws[FC1O + b * 256 + o] = fmaxf(s, 0.f);
}

// ---- fc2 ----
__global__ __launch_bounds__(256) void k_fc2(
    const float* __restrict__ w, const float* __restrict__ bias,
    const float* __restrict__ ws, float* __restrict__ out) {
    int b = blockIdx.x, o = threadIdx.x;
    __shared__ float hl[256];
    hl[o] = ws[FC1O + b * 256 + o];
    __syncthreads();
    if (o < 200) {
        float s = bias[o];
        const float* wp = w + o * 256;
#pragma unroll 8
        for (int c = 0; c < 256; ++c) s += hl[c] * wp[c];
        out[b * 200 + o] = s;
    }
}

extern "C" void kernel_launch(void* const* d_in, const int* in_sizes, int n_in,
                              void* d_out, int out_size, void* d_ws, size_t ws_size,
                              hipStream_t stream) {
    const float* x   = (const float*)d_in[0];
    const float* o1w = (const float*)d_in[1];
    const float* o1b = (const float*)d_in[2];
    const float* c1w = (const float*)d_in[3];
    const float* c1b = (const float*)d_in[4];
    const float* g1  = (const float*)d_in[5];
    const float* be1 = (const float*)d_in[6];
    const float* m1  = (const float*)d_in[7];
    const float* v1  = (const float*)d_in[8];
    const float* o2w = (const float*)d_in[9];
    const float* o2b = (const float*)d_in[10];
    const float* c2w = (const float*)d_in[11];
    const float* c2b = (const float*)d_in[12];
    const float* g2  = (const float*)d_in[13];
    const float* be2 = (const float*)d_in[14];
    const float* m2  = (const float*)d_in[15];
    const float* v2  = (const float*)d_in[16];
    const float* f1w = (const float*)d_in[17];
    const float* f1b = (const float*)d_in[18];
    const float* f2w = (const float*)d_in[19];
    const float* f2b = (const float*)d_in[20];
    float* ws  = (float*)d_ws;
    float* out = (float*)d_out;

    k_prep<<<354, 256, 0, stream>>>(o1w, c1w, o2w, c2w,
                                    c1b, g1, be1, m1, v1,
                                    c2b, g2, be2, m2, v2, ws);
    k_off1<<<512, 256, 0, stream>>>(x, o1b, ws);
    k_def1<<<512, 256, 0, stream>>>(x, ws);
    k_off2<<<512, 256, 0, stream>>>(o2b, ws);
    k_def2<<<2048, 256, 0, stream>>>(ws);
    k_fc1<<<32, 256, 0, stream>>>(f1w, f1b, ws);
    k_fc2<<<32, 256, 0, stream>>>(f2w, f2b, ws, out);
}

// Round 3
// 446.632 us; speedup vs baseline: 1.5887x; 1.1608x over previous
//
#include <hip/hip_runtime.h>

#define EPS 1e-5f

// ---- d_ws layout (float offsets) ----
#define W1OT 0          //   486  offset1_w [c*9+t][18]
#define W1T  512        //  1728  conv1_w   [c*9+t][64]
#define W2OT 2304       // 10368  offset2_w [t*64+c][18]
#define W2T  12800      // 73728 ushorts: conv2_w bf16 [t][n=cout][c]  (36864 float-slots)
#define SC1  86528      //    64  bn1 scale
#define SH1  86592      //    64  bn1 shift (bias folded)
#define SC2  86656      //   128  bn2 scale
#define SH2  86784      //   128  bn2 shift (bias folded)
#define POOL 86912      //  4096  pooled sums (zeroed in prep)
#define H1   99328      // 8388608  NHWC fp32 [b][hw][64]
#define OFF2 8487936    // 2359296  pixel-major [b][hw][18]
// total 10.8M floats = 41 MiB

typedef __attribute__((ext_vector_type(8))) short bhalf8;
typedef __attribute__((ext_vector_type(4))) float f32x4;

#define BPAD 72   // LDS k-stride (ushorts): 144 B -> b128 accesses at inherent-floor conflicts

struct Tap { int i00, i01, i10, i11; float w00, w01, w10, w11; };

__device__ __forceinline__ Tap make_tap(float py, float px) {
    float y0f = floorf(py), x0f = floorf(px);
    float wy = py - y0f, wx = px - x0f;
    bool by0 = (y0f >= 0.f)  && (y0f < 64.f);
    bool by1 = (y0f >= -1.f) && (y0f < 63.f);
    bool bx0 = (x0f >= 0.f)  && (x0f < 64.f);
    bool bx1 = (x0f >= -1.f) && (x0f < 63.f);
    int y0 = min(max((int)y0f, 0), 63);
    int y1 = min(max((int)y0f + 1, 0), 63);
    int x0 = min(max((int)x0f, 0), 63);
    int x1 = min(max((int)x0f + 1, 0), 63);
    Tap tp;
    tp.i00 = y0 * 64 + x0; tp.i01 = y0 * 64 + x1;
    tp.i10 = y1 * 64 + x0; tp.i11 = y1 * 64 + x1;
    tp.w00 = (by0 && bx0) ? (1.f - wy) * (1.f - wx) : 0.f;
    tp.w01 = (by0 && bx1) ? (1.f - wy) * wx         : 0.f;
    tp.w10 = (by1 && bx0) ? wy * (1.f - wx)         : 0.f;
    tp.w11 = (by1 && bx1) ? wy * wx                 : 0.f;
    return tp;
}

__device__ __forceinline__ ushort f2bf(float f) {
    union { float f; uint u; } a; a.f = f;
    uint u = a.u;
    return (ushort)((u + 0x7fffu + ((u >> 16) & 1u)) >> 16);   // RNE
}

// ---- prep: weight transposes + BN folding + pool zero ----
__global__ __launch_bounds__(256) void k_prep(
    const float* __restrict__ o1w, const float* __restrict__ c1w,
    const float* __restrict__ o2w, const float* __restrict__ c2w,
    const float* __restrict__ c1b, const float* __restrict__ g1,
    const float* __restrict__ be1, const float* __restrict__ m1,
    const float* __restrict__ v1,
    const float* __restrict__ c2b, const float* __restrict__ g2,
    const float* __restrict__ be2, const float* __restrict__ m2,
    const float* __restrict__ v2,
    float* __restrict__ ws) {
    int tid = blockIdx.x * 256 + threadIdx.x;
    if (tid < 486) {
        int k = tid / 18, co = tid - k * 18, c = k / 9, t = k - c * 9;
        ws[W1OT + tid] = o1w[(co * 3 + c) * 9 + t];
    } else if (tid < 2214) {
        int i = tid - 486;
        int k = i >> 6, co = i & 63, c = k / 9, t = k - c * 9;
        ws[W1T + i] = c1w[(co * 3 + c) * 9 + t];
    } else if (tid < 12582) {
        int i = tid - 2214;                  // i = (t*64+c)*18 + co
        int co = i % 18, k = i / 18, c = k & 63, t = k >> 6;
        ws[W2OT + i] = o2w[(co * 64 + c) * 9 + t];
    } else if (tid < 86310) {
        int i = tid - 12582;                 // i = t*8192 + n*64 + c
        int c = i & 63, n = (i >> 6) & 127, t = i >> 13;
        ((ushort*)(ws + W2T))[i] = f2bf(c2w[(n * 64 + c) * 9 + t]);
    } else if (tid < 86374) {
        int i = tid - 86310;
        float s = g1[i] * rsqrtf(v1[i] + EPS);
        ws[SC1 + i] = s;
        ws[SH1 + i] = (c1b[i] - m1[i]) * s + be1[i];
    } else if (tid < 86502) {
        int i = tid - 86374;
        float s = g2[i] * rsqrtf(v2[i] + EPS);
        ws[SC2 + i] = s;
        ws[SH2 + i] = (c2b[i] - m2[i]) * s + be2[i];
    } else if (tid < 90598) {
        ws[POOL + tid - 86502] = 0.f;
    }
}

// ---- fused offset-conv1 + deform conv1 (3->64) + BN + ReLU -> h1 NHWC ----
__global__ __launch_bounds__(256, 2) void k_def1(
    const float* __restrict__ x, const float* __restrict__ o1b,
    float* __restrict__ ws) {
    int tid = blockIdx.x * 256 + threadIdx.x;
    int b = tid >> 12, hw = tid & 4095, h = hw >> 6, w = hw & 63;
    // off1 in registers
    float off[18];
#pragma unroll
    for (int i = 0; i < 18; ++i) off[i] = o1b[i];
    const float* wt1 = ws + W1OT;
#pragma unroll
    for (int c = 0; c < 3; ++c) {
        const float* xp = x + (b * 3 + c) * 4096;
#pragma unroll
        for (int t = 0; t < 9; ++t) {
            int yy = h + t / 3 - 1, xx = w + t % 3 - 1;
            float pv = (yy >= 0 && yy < 64 && xx >= 0 && xx < 64) ? xp[yy * 64 + xx] : 0.f;
            const float* wp = wt1 + (c * 9 + t) * 18;
#pragma unroll
            for (int co = 0; co < 18; ++co) off[co] += pv * wp[co];
        }
    }
    // deformed gather
    float v[27];
#pragma unroll
    for (int t = 0; t < 9; ++t) {
        Tap tp = make_tap((float)(h + t / 3 - 1) + off[2 * t],
                          (float)(w + t % 3 - 1) + off[2 * t + 1]);
#pragma unroll
        for (int c = 0; c < 3; ++c) {
            const float* xp = x + (b * 3 + c) * 4096;
            v[c * 9 + t] = tp.w00 * xp[tp.i00] + tp.w01 * xp[tp.i01]
                         + tp.w10 * xp[tp.i10] + tp.w11 * xp[tp.i11];
        }
    }
    float acc[64];
#pragma unroll
    for (int i = 0; i < 64; ++i) acc[i] = 0.f;
    const float* wt = ws + W1T;
#pragma unroll
    for (int k = 0; k < 27; ++k) {
        float vk = v[k];
        const float* wp = wt + k * 64;
#pragma unroll
        for (int co = 0; co < 64; ++co) acc[co] += vk * wp[co];
    }
    const float* sc = ws + SC1;
    const float* sh = ws + SH1;
    float* op = ws + H1 + (size_t)(b * 4096 + hw) * 64;
#pragma unroll
    for (int i = 0; i < 16; ++i) {
        f32x4 o4;
#pragma unroll
        for (int j = 0; j < 4; ++j)
            o4[j] = fmaxf(acc[i * 4 + j] * sc[i * 4 + j] + sh[i * 4 + j], 0.f);
        *(f32x4*)(op + i * 4) = o4;
    }
}

// ---- offset conv2: h1 NHWC -> off2 pixel-major [b][hw][18] ----
__global__ __launch_bounds__(256, 4) void k_off2(
    const float* __restrict__ o2b, float* __restrict__ ws) {
    int tid = blockIdx.x * 256 + threadIdx.x;
    int b = tid >> 12, hw = tid & 4095, h = hw >> 6, w = hw & 63;
    float acc[18];
#pragma unroll
    for (int i = 0; i < 18; ++i) acc[i] = 0.f;
    const float* hp = ws + H1 + (size_t)b * 262144;
    const float* wt = ws + W2OT;
#pragma unroll
    for (int t = 0; t < 9; ++t) {
        int yy = h + t / 3 - 1, xx = w + t % 3 - 1;
        bool valid = (yy >= 0 && yy < 64 && xx >= 0 && xx < 64);
        const float* ip = hp + (size_t)(yy * 64 + xx) * 64;
#pragma unroll 4
        for (int c4 = 0; c4 < 16; ++c4) {
            f32x4 pv = (f32x4)0.f;
            if (valid) pv = *(const f32x4*)(ip + c4 * 4);
            const float* wp = wt + (t * 64 + c4 * 4) * 18;
#pragma unroll
            for (int j = 0; j < 4; ++j)
#pragma unroll
                for (int co = 0; co < 18; ++co)
                    acc[co] += pv[j] * wp[j * 18 + co];
        }
    }
    float* op = ws + OFF2 + (size_t)(b * 4096 + hw) * 18;
#pragma unroll
    for (int co = 0; co < 18; ++co) op[co] = acc[co] + o2b[co];
}

// ---- deform conv2 (64->128) implicit-GEMM bf16 MFMA + BN + ReLU + pool ----
// Grid 1024: g -> (b = g>>5, rows h2=(g&31)*2, h2+1). 256 thr = 4 waves.
// A-frags gathered straight into MFMA A layout (no LDS); B staged per tap, prefetched.
__global__ __launch_bounds__(256, 2) void k_def2(float* __restrict__ ws) {
    __shared__ ushort Blds[128 * BPAD];
    int g = blockIdx.x;
    int b = g >> 5, h2 = (g & 31) * 2;
    int tid = threadIdx.x, lane = tid & 63, wv = tid >> 6;
    int r = lane & 15, q = lane >> 4;
    int px = wv * 16 + r;                   // pixel x for both m-tiles
    const float* hp = ws + H1 + (size_t)b * 262144;
    const float* o2 = ws + OFF2 + (size_t)b * 4096 * 18;
    const ushort* wB = (const ushort*)(ws + W2T);
    int bn = tid >> 1, bc = (tid & 1) * 32;

    uint4 br0, br1, br2, br3;               // B prefetch regs (tap 0)
    {
        const uint4* s4 = (const uint4*)(wB + bn * 64 + bc);
        br0 = s4[0]; br1 = s4[1]; br2 = s4[2]; br3 = s4[3];
    }
    f32x4 acc[2][8];
#pragma unroll
    for (int i = 0; i < 2; ++i)
#pragma unroll
        for (int j = 0; j < 8; ++j) acc[i][j] = (f32x4)0.f;

    for (int t = 0; t < 9; ++t) {
        // offsets + taps for both rows (before barriers; overlaps other waves' MFMA)
        float2 oA = *(const float2*)(o2 + (size_t)(h2 * 64 + px) * 18 + 2 * t);
        float2 oB = *(const float2*)(o2 + (size_t)((h2 + 1) * 64 + px) * 18 + 2 * t);
        Tap tpA = make_tap((float)(h2 + t / 3 - 1) + oA.x, (float)(px + t % 3 - 1) + oA.y);
        Tap tpB = make_tap((float)(h2 + 1 + t / 3 - 1) + oB.x, (float)(px + t % 3 - 1) + oB.y);
        if (t) __syncthreads();             // previous tap's B readers done
        {
            ushort* dst = Blds + bn * BPAD + bc;
            *(uint4*)(dst)      = br0;
            *(uint4*)(dst + 8)  = br1;
            *(uint4*)(dst + 16) = br2;
            *(uint4*)(dst + 24) = br3;
        }
        if (t < 8) {                        // prefetch next tap's B (in flight over MFMA)
            const uint4* s4 = (const uint4*)(wB + ((t + 1) * 128 + bn) * 64 + bc);
            br0 = s4[0]; br1 = s4[1]; br2 = s4[2]; br3 = s4[3];
        }
        __syncthreads();
#pragma unroll
        for (int ks = 0; ks < 2; ++ks) {
            int ko = ks * 32 + q * 8;       // this lane's 8 channels
            bhalf8 bf[8];
#pragma unroll
            for (int nt = 0; nt < 8; ++nt)
                bf[nt] = *(const bhalf8*)(Blds + (nt * 16 + r) * BPAD + ko);
#pragma unroll
            for (int mi = 0; mi < 2; ++mi) {
                const Tap tp = mi ? tpB : tpA;
                const float* p00 = hp + (size_t)tp.i00 * 64 + ko;
                const float* p01 = hp + (size_t)tp.i01 * 64 + ko;
                const float* p10 = hp + (size_t)tp.i10 * 64 + ko;
                const float* p11 = hp + (size_t)tp.i11 * 64 + ko;
                f32x4 a00 = *(const f32x4*)(p00), b00 = *(const f32x4*)(p00 + 4);
                f32x4 a01 = *(const f32x4*)(p01), b01 = *(const f32x4*)(p01 + 4);
                f32x4 a10 = *(const f32x4*)(p10), b10 = *(const f32x4*)(p10 + 4);
                f32x4 a11 = *(const f32x4*)(p11), b11 = *(const f32x4*)(p11 + 4);
                f32x4 lo = tp.w00 * a00 + tp.w01 * a01 + tp.w10 * a10 + tp.w11 * a11;
                f32x4 hi = tp.w00 * b00 + tp.w01 * b01 + tp.w10 * b10 + tp.w11 * b11;
                bhalf8 af;
#pragma unroll
                for (int j = 0; j < 4; ++j) {
                    af[j]     = (short)f2bf(lo[j]);
                    af[j + 4] = (short)f2bf(hi[j]);
                }
#pragma unroll
                for (int nt = 0; nt < 8; ++nt)
                    acc[mi][nt] = __builtin_amdgcn_mfma_f32_16x16x32_bf16(af, bf[nt], acc[mi][nt], 0, 0, 0);
            }
        }
    }
    // epilogue: BN + ReLU + pool
    const float* sc = ws + SC2;
    const float* sh = ws + SH2;
    float* pool = ws + POOL;
#pragma unroll
    for (int nt = 0; nt < 8; ++nt) {
        int col = nt * 16 + r;
        float s0 = sc[col], s1 = sh[col];
        float s = 0.f;
#pragma unroll
        for (int mi = 0; mi < 2; ++mi)
#pragma unroll
            for (int rr = 0; rr < 4; ++rr)
                s += fmaxf(acc[mi][nt][rr] * s0 + s1, 0.f);
        s += __shfl_xor(s, 16);
        s += __shfl_xor(s, 32);
        if (lane < 16) atomicAdd(&pool[b * 128 + col], s);
    }
}

// ---- fused fc1+relu+fc2 ----
__global__ __launch_bounds__(256) void k_fc(
    const float* __restrict__ w1, const float* __restrict__ b1,
    const float* __restrict__ w2, const float* __restrict__ b2,
    const float* __restrict__ ws, float* __restrict__ out) {
    int b = blockIdx.x, o = threadIdx.x;
    __shared__ float pl[128];
    __shared__ float hl[256];
    if (o < 128) pl[o] = ws[POOL + b * 128 + o] * (1.f / 4096.f);
    __syncthreads();
    float s = b1[o];
    const float* wp = w1 + o * 128;
#pragma unroll 8
    for (int c = 0; c < 128; ++c) s += pl[c] * wp[c];
    hl[o] = fmaxf(s, 0.f);
    __syncthreads();
    if (o < 200) {
        float s2 = b2[o];
        const float* wp2 = w2 + o * 256;
#pragma unroll 8
        for (int c = 0; c < 256; ++c) s2 += hl[c] * wp2[c];
        out[b * 200 + o] = s2;
    }
}

extern "C" void kernel_launch(void* const* d_in, const int* in_sizes, int n_in,
                              void* d_out, int out_size, void* d_ws, size_t ws_size,
                              hipStream_t stream) {
    const float* x   = (const float*)d_in[0];
    const float* o1w = (const float*)d_in[1];
    const float* o1b = (const float*)d_in[2];
    const float* c1w = (const float*)d_in[3];
    const float* c1b = (const float*)d_in[4];
    const float* g1  = (const float*)d_in[5];
    const float* be1 = (const float*)d_in[6];
    const float* m1  = (const float*)d_in[7];
    const float* v1  = (const float*)d_in[8];
    const float* o2w = (const float*)d_in[9];
    const float* o2b = (const float*)d_in[10];
    const float* c2w = (const float*)d_in[11];
    const float* c2b = (const float*)d_in[12];
    const float* g2  = (const float*)d_in[13];
    const float* be2 = (const float*)d_in[14];
    const float* m2  = (const float*)d_in[15];
    const float* v2  = (const float*)d_in[16];
    const float* f1w = (const float*)d_in[17];
    const float* f1b = (const float*)d_in[18];
    const float* f2w = (const float*)d_in[19];
    const float* f2b = (const float*)d_in[20];
    float* ws  = (float*)d_ws;
    float* out = (float*)d_out;

    k_prep<<<354, 256, 0, stream>>>(o1w, c1w, o2w, c2w,
                                    c1b, g1, be1, m1, v1,
                                    c2b, g2, be2, m2, v2, ws);
    k_def1<<<512, 256, 0, stream>>>(x, o1b, ws);
    k_off2<<<512, 256, 0, stream>>>(o2b, ws);
    k_def2<<<1024, 256, 0, stream>>>(ws);
    k_fc<<<32, 256, 0, stream>>>(f1w, f1b, f2w, f2b, ws, out);
}